// Round 1
// baseline (404.691 us; speedup 1.0000x reference)
//
#include <hip/hip_runtime.h>
#include <hip/hip_bf16.h>

#define B_ 8
#define S_ 2048
#define D_ 1024
#define H_ 64

typedef __attribute__((ext_vector_type(8))) short bf16x8;
typedef __attribute__((ext_vector_type(4))) float f32x4;

static __device__ __forceinline__ unsigned short f2bf(float f) {
  union { float f; unsigned u; } v; v.f = f;
  unsigned r = v.u + 0x7FFFu + ((v.u >> 16) & 1u);
  return (unsigned short)(r >> 16);
}

// Build Wt [192][1024] bf16: rows 0..63 = Wq columns, 64..127 = Wk, 128..191 = Wv.
__global__ __launch_bounds__(256) void wprep_kernel(const float* __restrict__ Wk,
                                                    const float* __restrict__ Wq,
                                                    const float* __restrict__ Wv,
                                                    unsigned short* __restrict__ Wt) {
  const int c = blockIdx.x;  // 0..191
  const float* W = (c < 64) ? Wq : ((c < 128) ? Wk : Wv);
  const int cc = c & 63;
  for (int d = threadIdx.x; d < D_; d += blockDim.x)
    Wt[c * D_ + d] = f2bf(W[d * H_ + cc]);
}

// QKV projection: [16384 x 1024] @ [1024 x 192] via mfma_f32_16x16x32_bf16.
// Grid: 64 M-blocks (256 rows each) x 4 N-blocks (48 cols each) = 256 blocks.
// Each wave: 64 rows x 48 cols = acc[4][3] f32x4.
__global__ __launch_bounds__(256) void qkv_kernel(const float* __restrict__ x,
                                                  const unsigned short* __restrict__ Wt,
                                                  float* __restrict__ Q,
                                                  float* __restrict__ K,
                                                  float* __restrict__ V) {
  const int mb = blockIdx.x >> 2;
  const int nb = blockIdx.x & 3;
  const int wave = threadIdx.x >> 6;
  const int lane = threadIdx.x & 63;
  const int r = lane & 15;
  const int g = lane >> 4;

  const long row0 = (long)mb * 256 + wave * 64;
  const int col0 = nb * 48;

  f32x4 acc[4][3];
#pragma unroll
  for (int mi = 0; mi < 4; ++mi)
#pragma unroll
    for (int ni = 0; ni < 3; ++ni)
      acc[mi][ni] = (f32x4){0.f, 0.f, 0.f, 0.f};

  const float* xp = x + (row0 + r) * (long)D_;
  const unsigned short* wp = Wt + (long)(col0 + r) * D_;

  for (int k0 = 0; k0 < D_; k0 += 32) {
    const int kk = k0 + g * 8;
    bf16x8 a[4], b[3];
#pragma unroll
    for (int mi = 0; mi < 4; ++mi) {
      const float* p = xp + (long)mi * 16 * D_ + kk;
      float4 lo = *(const float4*)(p);
      float4 hi = *(const float4*)(p + 4);
      bf16x8 t;
      t[0] = (short)f2bf(lo.x); t[1] = (short)f2bf(lo.y);
      t[2] = (short)f2bf(lo.z); t[3] = (short)f2bf(lo.w);
      t[4] = (short)f2bf(hi.x); t[5] = (short)f2bf(hi.y);
      t[6] = (short)f2bf(hi.z); t[7] = (short)f2bf(hi.w);
      a[mi] = t;
    }
#pragma unroll
    for (int ni = 0; ni < 3; ++ni)
      b[ni] = *(const bf16x8*)(wp + (long)ni * 16 * D_ + kk);
#pragma unroll
    for (int mi = 0; mi < 4; ++mi)
#pragma unroll
      for (int ni = 0; ni < 3; ++ni)
        acc[mi][ni] = __builtin_amdgcn_mfma_f32_16x16x32_bf16(a[mi], b[ni], acc[mi][ni], 0, 0, 0);
  }

#pragma unroll
  for (int mi = 0; mi < 4; ++mi) {
#pragma unroll
    for (int ni = 0; ni < 3; ++ni) {
      const int col = col0 + ni * 16 + r;
      float* dst = (col < 64) ? Q : ((col < 128) ? K : V);
      const int c = col & 63;
#pragma unroll
      for (int i = 0; i < 4; ++i) {
        const long row = row0 + mi * 16 + g * 4 + i;
        dst[row * H_ + c] = acc[mi][ni][i];
      }
    }
  }
}

// Causal flash attention, fp32 vector. Block = 4 waves = 4 consecutive q rows.
__global__ __launch_bounds__(256) void attn_kernel(const float* __restrict__ Q,
                                                   const float* __restrict__ K,
                                                   const float* __restrict__ V,
                                                   float* __restrict__ out) {
  __shared__ float kt[64][65];
  __shared__ float vt[64][65];
  __shared__ float qs[4][64];
  __shared__ float ps[4][64];

  const int b = blockIdx.x >> 9;   // 512 q-groups per batch
  const int qg = blockIdx.x & 511;
  const int q0 = qg * 4;
  const int wave = threadIdx.x >> 6;
  const int lane = threadIdx.x & 63;
  const int q = q0 + wave;

  const float* Kb = K + (long)b * S_ * H_;
  const float* Vb = V + (long)b * S_ * H_;

  qs[wave][lane] = Q[((long)b * S_ + q) * H_ + lane] * 0.125f;  // 1/sqrt(64)

  float m = -INFINITY, l = 0.f, z = 0.f;
  const int npass = (q0 + 3) / 64 + 1;  // q0 % 4 == 0 -> group never splits a 64-tile

  for (int p = 0; p < npass; ++p) {
    const int k0 = p * 64;
    __syncthreads();
    for (int idx = threadIdx.x; idx < 64 * 64; idx += 256) {
      const int j = idx >> 6, h = idx & 63;
      kt[j][h] = Kb[(long)(k0 + j) * H_ + h];
      vt[j][h] = Vb[(long)(k0 + j) * H_ + h];
    }
    __syncthreads();

    // scores: lane plays role of k-index j
    float s = -INFINITY;
    if (k0 + lane <= q) {
      float a0 = 0.f;
#pragma unroll
      for (int d = 0; d < 64; ++d) a0 += qs[wave][d] * kt[lane][d];
      s = a0;
    }
    float tm = s;
#pragma unroll
    for (int off = 32; off >= 1; off >>= 1) tm = fmaxf(tm, __shfl_xor(tm, off));
    const float mnew = fmaxf(m, tm);               // finite: lane j==q-k0 always valid
    const float scale = __expf(m - mnew);          // first pass: exp(-inf)=0
    const float pj = __expf(s - mnew);             // masked lanes: exp(-inf)=0
    float ts = pj;
#pragma unroll
    for (int off = 32; off >= 1; off >>= 1) ts += __shfl_xor(ts, off);
    l = l * scale + ts;
    z *= scale;
    ps[wave][lane] = pj;
#pragma unroll
    for (int j = 0; j < 64; ++j) z += ps[wave][j] * vt[j][lane];  // lane plays role of h
    m = mnew;
  }
  out[((long)b * S_ + q) * H_ + lane] = z / l;
}

extern "C" void kernel_launch(void* const* d_in, const int* in_sizes, int n_in,
                              void* d_out, int out_size, void* d_ws, size_t ws_size,
                              hipStream_t stream) {
  const float* x  = (const float*)d_in[0];
  const float* Wk = (const float*)d_in[1];
  const float* Wq = (const float*)d_in[2];
  const float* Wv = (const float*)d_in[3];
  float* out = (float*)d_out;

  float* Q = (float*)d_ws;                    // 4 MiB
  float* K = Q + (long)B_ * S_ * H_;          // 4 MiB
  float* V = K + (long)B_ * S_ * H_;          // 4 MiB
  unsigned short* Wt = (unsigned short*)(V + (long)B_ * S_ * H_);  // 384 KiB

  wprep_kernel<<<192, 256, 0, stream>>>(Wk, Wq, Wv, Wt);
  qkv_kernel<<<256, 256, 0, stream>>>(x, Wt, Q, K, V);
  attn_kernel<<<B_ * (S_ / 4), 256, 0, stream>>>(Q, K, V, out);
}

// Round 2
// 154.502 us; speedup vs baseline: 2.6193x; 2.6193x over previous
//
#include <hip/hip_runtime.h>
#include <hip/hip_bf16.h>

#define B_ 8
#define S_ 2048
#define D_ 1024
#define H_ 64

typedef __attribute__((ext_vector_type(8))) short bf16x8;
typedef __attribute__((ext_vector_type(4))) float f32x4;
typedef unsigned short u16;

// fold 1/sqrt(64) and log2(e) into Q so softmax can use exp2
#define QSCALE 0.18033688011112042f

static __device__ __forceinline__ u16 f2bf(float f) {
  union { float f; unsigned u; } v; v.f = f;
  unsigned r = v.u + 0x7FFFu + ((v.u >> 16) & 1u);
  return (u16)(r >> 16);
}

// Build Wt [192][1024] bf16: rows 0..63 = Wq columns, 64..127 = Wk, 128..191 = Wv.
__global__ __launch_bounds__(256) void wprep_kernel(const float* __restrict__ Wk,
                                                    const float* __restrict__ Wq,
                                                    const float* __restrict__ Wv,
                                                    u16* __restrict__ Wt) {
  const int c = blockIdx.x;  // 0..191
  const float* W = (c < 64) ? Wq : ((c < 128) ? Wk : Wv);
  const int cc = c & 63;
  for (int d = threadIdx.x; d < D_; d += blockDim.x)
    Wt[c * D_ + d] = f2bf(W[d * H_ + cc]);
}

// QKV projection: [16384 x 1024] @ [1024 x 192] via mfma_f32_16x16x32_bf16.
// Outputs: Qb bf16 [B*S][64] (pre-scaled), Kb bf16 [B*S][64], Vt bf16 [B][64][S].
__global__ __launch_bounds__(256) void qkv_kernel(const float* __restrict__ x,
                                                  const u16* __restrict__ Wt,
                                                  u16* __restrict__ Qb,
                                                  u16* __restrict__ Kb,
                                                  u16* __restrict__ Vt) {
  const int mb = blockIdx.x >> 2;
  const int nb = blockIdx.x & 3;
  const int wave = threadIdx.x >> 6;
  const int lane = threadIdx.x & 63;
  const int r = lane & 15;
  const int g = lane >> 4;

  const long row0 = (long)mb * 256 + wave * 64;
  const int col0 = nb * 48;

  f32x4 acc[4][3];
#pragma unroll
  for (int mi = 0; mi < 4; ++mi)
#pragma unroll
    for (int ni = 0; ni < 3; ++ni)
      acc[mi][ni] = (f32x4){0.f, 0.f, 0.f, 0.f};

  const float* xp = x + (row0 + r) * (long)D_;
  const u16* wp = Wt + (long)(col0 + r) * D_;

  for (int k0 = 0; k0 < D_; k0 += 32) {
    const int kk = k0 + g * 8;
    bf16x8 a[4], b[3];
#pragma unroll
    for (int mi = 0; mi < 4; ++mi) {
      const float* p = xp + (long)mi * 16 * D_ + kk;
      float4 lo = *(const float4*)(p);
      float4 hi = *(const float4*)(p + 4);
      bf16x8 t;
      t[0] = (short)f2bf(lo.x); t[1] = (short)f2bf(lo.y);
      t[2] = (short)f2bf(lo.z); t[3] = (short)f2bf(lo.w);
      t[4] = (short)f2bf(hi.x); t[5] = (short)f2bf(hi.y);
      t[6] = (short)f2bf(hi.z); t[7] = (short)f2bf(hi.w);
      a[mi] = t;
    }
#pragma unroll
    for (int ni = 0; ni < 3; ++ni)
      b[ni] = *(const bf16x8*)(wp + (long)ni * 16 * D_ + kk);
#pragma unroll
    for (int mi = 0; mi < 4; ++mi)
#pragma unroll
      for (int ni = 0; ni < 3; ++ni)
        acc[mi][ni] = __builtin_amdgcn_mfma_f32_16x16x32_bf16(a[mi], b[ni], acc[mi][ni], 0, 0, 0);
  }

#pragma unroll
  for (int mi = 0; mi < 4; ++mi) {
#pragma unroll
    for (int ni = 0; ni < 3; ++ni) {
      const int col = col0 + ni * 16 + r;
#pragma unroll
      for (int i = 0; i < 4; ++i) {
        const long rr = row0 + mi * 16 + g * 4 + i;
        const float val = acc[mi][ni][i];
        if (col < 64) {
          Qb[rr * H_ + col] = f2bf(val * QSCALE);
        } else if (col < 128) {
          Kb[rr * H_ + (col - 64)] = f2bf(val);
        } else {
          Vt[((rr >> 11) * H_ + (col - 128)) * (long)S_ + (rr & 2047)] = f2bf(val);
        }
      }
    }
  }
}

// MFMA causal flash attention. 1 wave = 16 q rows; block = 4 waves with
// balanced q-tile assignment {j, 63-j, 64+j, 127-j}; grid = 8 batches x 32.
__global__ __launch_bounds__(256) void attn2_kernel(const u16* __restrict__ Qb,
                                                    const u16* __restrict__ Kb,
                                                    const u16* __restrict__ Vt,
                                                    float* __restrict__ out) {
  __shared__ u16 plds[4][16 * 72];

  const int b = blockIdx.x >> 5;
  const int j = blockIdx.x & 31;
  const int w = threadIdx.x >> 6;
  const int lane = threadIdx.x & 63;
  const int r = lane & 15;
  const int g = lane >> 4;

  int qt;
  if (w == 0) qt = j;
  else if (w == 1) qt = 63 - j;
  else if (w == 2) qt = 64 + j;
  else qt = 127 - j;
  const int q0 = qt << 4;

  // Q A-fragments (hoisted): a[i] = Q[q0 + (lane&15)][32*kd + 8*(lane>>4) + i]
  const u16* Qp = Qb + ((long)(b * S_ + q0 + r)) * H_ + 8 * g;
  const bf16x8 aq0 = *(const bf16x8*)Qp;
  const bf16x8 aq1 = *(const bf16x8*)(Qp + 32);

  const u16* Kbase = Kb + (long)b * S_ * H_ + (long)r * H_ + 8 * g;
  const u16* Vbase = Vt + (long)b * H_ * S_ + (long)r * S_ + 8 * g;

  f32x4 o[4];
#pragma unroll
  for (int nf = 0; nf < 4; ++nf) o[nf] = (f32x4){0.f, 0.f, 0.f, 0.f};
  float mrow[4] = {-INFINITY, -INFINITY, -INFINITY, -INFINITY};
  float lrow[4] = {0.f, 0.f, 0.f, 0.f};

  u16* pw = plds[w];
  const int lastT = q0 >> 6;

  for (int kt = 0; kt <= lastT; ++kt) {
    const int k0 = kt << 6;

    // ---- QK^T: S[16q x 64k] ----
    f32x4 s[4];
#pragma unroll
    for (int nf = 0; nf < 4; ++nf) {
      const u16* Kp = Kbase + (long)(k0 + nf * 16) * H_;
      const bf16x8 bk0 = *(const bf16x8*)(Kp);
      const bf16x8 bk1 = *(const bf16x8*)(Kp + 32);
      f32x4 t = (f32x4){0.f, 0.f, 0.f, 0.f};
      t = __builtin_amdgcn_mfma_f32_16x16x32_bf16(aq0, bk0, t, 0, 0, 0);
      t = __builtin_amdgcn_mfma_f32_16x16x32_bf16(aq1, bk1, t, 0, 0, 0);
      s[nf] = t;
    }

    if (kt == lastT) {  // causal mask on the diagonal tile only
#pragma unroll
      for (int nf = 0; nf < 4; ++nf)
#pragma unroll
        for (int i = 0; i < 4; ++i) {
          const int k = k0 + nf * 16 + r;
          const int q = q0 + 4 * g + i;
          if (k > q) s[nf][i] = -INFINITY;
        }
    }

    // ---- online softmax (rows live in lane-groups of 16) ----
    float fm[4];
#pragma unroll
    for (int i = 0; i < 4; ++i)
      fm[i] = fmaxf(fmaxf(s[0][i], s[1][i]), fmaxf(s[2][i], s[3][i]));
#pragma unroll
    for (int off = 8; off >= 1; off >>= 1)
#pragma unroll
      for (int i = 0; i < 4; ++i)
        fm[i] = fmaxf(fm[i], __shfl_xor(fm[i], off));

    float sc[4];
#pragma unroll
    for (int i = 0; i < 4; ++i) {
      const float mn = fmaxf(mrow[i], fm[i]);
      sc[i] = exp2f(mrow[i] - mn);
      mrow[i] = mn;
    }

    float ps[4] = {0.f, 0.f, 0.f, 0.f};
#pragma unroll
    for (int nf = 0; nf < 4; ++nf)
#pragma unroll
      for (int i = 0; i < 4; ++i) {
        const float p = exp2f(s[nf][i] - mrow[i]);
        s[nf][i] = p;
        ps[i] += p;
      }
#pragma unroll
    for (int off = 8; off >= 1; off >>= 1)
#pragma unroll
      for (int i = 0; i < 4; ++i)
        ps[i] += __shfl_xor(ps[i], off);

#pragma unroll
    for (int i = 0; i < 4; ++i) lrow[i] = lrow[i] * sc[i] + ps[i];
#pragma unroll
    for (int nf = 0; nf < 4; ++nf)
#pragma unroll
      for (int i = 0; i < 4; ++i) o[nf][i] *= sc[i];

    // ---- P -> LDS (bf16), re-fragment for PV A-operand ----
#pragma unroll
    for (int nf = 0; nf < 4; ++nf)
#pragma unroll
      for (int i = 0; i < 4; ++i)
        pw[(4 * g + i) * 72 + nf * 16 + r] = f2bf(s[nf][i]);

    const bf16x8 pa0 = *(const bf16x8*)(pw + r * 72 + 8 * g);
    const bf16x8 pa1 = *(const bf16x8*)(pw + r * 72 + 32 + 8 * g);

    // ---- PV: O += P[16x64] * V[64x64] ----
#pragma unroll
    for (int nf = 0; nf < 4; ++nf) {
      const u16* Vp = Vbase + (long)(nf * 16) * S_ + k0;
      const bf16x8 bv0 = *(const bf16x8*)(Vp);
      const bf16x8 bv1 = *(const bf16x8*)(Vp + 32);
      o[nf] = __builtin_amdgcn_mfma_f32_16x16x32_bf16(pa0, bv0, o[nf], 0, 0, 0);
      o[nf] = __builtin_amdgcn_mfma_f32_16x16x32_bf16(pa1, bv1, o[nf], 0, 0, 0);
    }
  }

  float inv[4];
#pragma unroll
  for (int i = 0; i < 4; ++i) inv[i] = 1.f / lrow[i];
#pragma unroll
  for (int nf = 0; nf < 4; ++nf)
#pragma unroll
    for (int i = 0; i < 4; ++i)
      out[((long)(b * S_ + q0 + 4 * g + i)) * H_ + nf * 16 + r] = o[nf][i] * inv[i];
}

extern "C" void kernel_launch(void* const* d_in, const int* in_sizes, int n_in,
                              void* d_out, int out_size, void* d_ws, size_t ws_size,
                              hipStream_t stream) {
  const float* x  = (const float*)d_in[0];
  const float* Wk = (const float*)d_in[1];
  const float* Wq = (const float*)d_in[2];
  const float* Wv = (const float*)d_in[3];
  float* out = (float*)d_out;

  u16* Qb = (u16*)d_ws;                                   // 2 MiB
  u16* Kb = Qb + (long)B_ * S_ * H_;                      // 2 MiB
  u16* Vt = Kb + (long)B_ * S_ * H_;                      // 2 MiB
  u16* Wt = Vt + (long)B_ * S_ * H_;                      // 384 KiB

  wprep_kernel<<<192, 256, 0, stream>>>(Wk, Wq, Wv, Wt);
  qkv_kernel<<<256, 256, 0, stream>>>(x, Wt, Qb, Kb, Vt);
  attn2_kernel<<<B_ * 32, 256, 0, stream>>>(Qb, Kb, Vt, out);
}

// Round 3
// 146.950 us; speedup vs baseline: 2.7539x; 1.0514x over previous
//
#include <hip/hip_runtime.h>
#include <hip/hip_bf16.h>

#define B_ 8
#define S_ 2048
#define D_ 1024
#define H_ 64

typedef __attribute__((ext_vector_type(8))) short bf16x8;
typedef __attribute__((ext_vector_type(4))) float f32x4;
typedef __attribute__((ext_vector_type(4))) unsigned short u16x4;
typedef unsigned short u16;

// fold 1/sqrt(64) and log2(e) into Q so softmax can use exp2
#define QSCALE 0.18033688011112042f

static __device__ __forceinline__ u16 f2bf(float f) {
  union { float f; unsigned u; } v; v.f = f;
  unsigned r = v.u + 0x7FFFu + ((v.u >> 16) & 1u);
  return (u16)(r >> 16);
}

// Build Wt [192][1024] bf16: rows 0..63 = Wq cols, 64..127 = Wk, 128..191 = Wv.
__global__ __launch_bounds__(256) void wprep_kernel(const float* __restrict__ Wk,
                                                    const float* __restrict__ Wq,
                                                    const float* __restrict__ Wv,
                                                    u16* __restrict__ Wt) {
  const int c = blockIdx.x;  // 0..191
  const float* W = (c < 64) ? Wq : ((c < 128) ? Wk : Wv);
  const int cc = c & 63;
  for (int d = threadIdx.x; d < D_; d += blockDim.x)
    Wt[c * D_ + d] = f2bf(W[d * H_ + cc]);
}

// QKV projection. 1 wave per 16 rows, all 192 cols (12 N-frags) -> x read once.
// Outputs: Qb bf16 [B*S][64] (pre-scaled), Kb bf16 [B*S][64], Vt bf16 [B][64][S].
__global__ __launch_bounds__(64) void qkv_kernel(const float* __restrict__ x,
                                                 const u16* __restrict__ Wt,
                                                 u16* __restrict__ Qb,
                                                 u16* __restrict__ Kb,
                                                 u16* __restrict__ Vt) {
  const long row0 = (long)blockIdx.x * 16;
  const int lane = threadIdx.x & 63;
  const int r = lane & 15;
  const int g = lane >> 4;

  f32x4 acc[12];
#pragma unroll
  for (int nf = 0; nf < 12; ++nf) acc[nf] = (f32x4){0.f, 0.f, 0.f, 0.f};

  const float* xp = x + (row0 + r) * (long)D_ + 8 * g;
  const u16* wp = Wt + (long)r * D_ + 8 * g;

#pragma unroll 2
  for (int k0 = 0; k0 < D_; k0 += 32) {
    float4 lo = *(const float4*)(xp);
    float4 hi = *(const float4*)(xp + 4);
    bf16x8 a;
    a[0] = (short)f2bf(lo.x); a[1] = (short)f2bf(lo.y);
    a[2] = (short)f2bf(lo.z); a[3] = (short)f2bf(lo.w);
    a[4] = (short)f2bf(hi.x); a[5] = (short)f2bf(hi.y);
    a[6] = (short)f2bf(hi.z); a[7] = (short)f2bf(hi.w);
#pragma unroll
    for (int nf = 0; nf < 12; ++nf) {
      const bf16x8 b = *(const bf16x8*)(wp + (long)nf * 16 * D_);
      acc[nf] = __builtin_amdgcn_mfma_f32_16x16x32_bf16(a, b, acc[nf], 0, 0, 0);
    }
    xp += 32; wp += 32;
  }

  const int bb = (int)(row0 >> 11);
  const int srow = (int)(row0 & 2047);

#pragma unroll
  for (int nf = 0; nf < 4; ++nf) {   // Q: cols 0..63, pre-scaled
    const int col = nf * 16 + r;
#pragma unroll
    for (int i = 0; i < 4; ++i)
      Qb[(row0 + 4 * g + i) * H_ + col] = f2bf(acc[nf][i] * QSCALE);
  }
#pragma unroll
  for (int nf = 4; nf < 8; ++nf) {   // K: cols 64..127
    const int col = (nf - 4) * 16 + r;
#pragma unroll
    for (int i = 0; i < 4; ++i)
      Kb[(row0 + 4 * g + i) * H_ + col] = f2bf(acc[nf][i]);
  }
#pragma unroll
  for (int nf = 8; nf < 12; ++nf) {  // V^T: [b][h][s], 4 consecutive s -> 8B store
    const int col = (nf - 8) * 16 + r;
    u16x4 vp;
#pragma unroll
    for (int i = 0; i < 4; ++i) vp[i] = f2bf(acc[nf][i]);
    *(u16x4*)(Vt + ((long)(bb * H_ + col)) * S_ + srow + 4 * g) = vp;
  }
}

// MFMA causal flash attention with 2-way KV split.
// Block = 4 waves: waves {0,1} = q-tile j (kv halves 0,1), waves {2,3} = q-tile 127-j.
// Grid = 8 batches x 64 pairs = 512 blocks -> 2 blocks/CU.
__global__ __launch_bounds__(256) void attn3_kernel(const u16* __restrict__ Qb,
                                                    const u16* __restrict__ Kb,
                                                    const u16* __restrict__ Vt,
                                                    float* __restrict__ out) {
  __shared__ u16 plds[4][16 * 72];
  __shared__ float plo[4][16][68];
  __shared__ float pml[4][2][16];

  const int b = blockIdx.x >> 6;
  const int j = blockIdx.x & 63;
  const int w = threadIdx.x >> 6;
  const int lane = threadIdx.x & 63;
  const int r = lane & 15;
  const int g = lane >> 4;

  const int qt = (w < 2) ? j : (127 - j);
  const int s = w & 1;
  const int q0 = qt << 4;
  const int T = (qt >> 2) + 1;          // # of 64-wide kv tiles
  const int half = (T + 1) >> 1;
  const int start = s ? half : 0;
  const int end = s ? T : half;

  // Q A-fragments (hoisted)
  const u16* Qp = Qb + ((long)(b * S_ + q0 + r)) * H_ + 8 * g;
  const bf16x8 aq0 = *(const bf16x8*)Qp;
  const bf16x8 aq1 = *(const bf16x8*)(Qp + 32);

  const u16* Kbase = Kb + (long)b * S_ * H_ + (long)r * H_ + 8 * g;
  const u16* Vbase = Vt + (long)b * H_ * S_ + (long)r * S_ + 8 * g;

  f32x4 o[4];
#pragma unroll
  for (int nf = 0; nf < 4; ++nf) o[nf] = (f32x4){0.f, 0.f, 0.f, 0.f};
  float mrow[4] = {-INFINITY, -INFINITY, -INFINITY, -INFINITY};
  float lrow[4] = {0.f, 0.f, 0.f, 0.f};

  u16* pw = plds[w];

  bf16x8 kc[8];
  if (start < end) {
    const int k0 = start << 6;
#pragma unroll
    for (int nf = 0; nf < 4; ++nf) {
      const u16* Kp = Kbase + (long)(k0 + nf * 16) * H_;
      kc[2 * nf] = *(const bf16x8*)(Kp);
      kc[2 * nf + 1] = *(const bf16x8*)(Kp + 32);
    }
  }

  for (int kt = start; kt < end; ++kt) {
    const int k0 = kt << 6;

    // ---- QK^T ----
    f32x4 sf[4];
#pragma unroll
    for (int nf = 0; nf < 4; ++nf) {
      f32x4 t = (f32x4){0.f, 0.f, 0.f, 0.f};
      t = __builtin_amdgcn_mfma_f32_16x16x32_bf16(aq0, kc[2 * nf], t, 0, 0, 0);
      t = __builtin_amdgcn_mfma_f32_16x16x32_bf16(aq1, kc[2 * nf + 1], t, 0, 0, 0);
      sf[nf] = t;
    }

    // ---- early V loads (fly under softmax) ----
    bf16x8 vv[8];
#pragma unroll
    for (int nf = 0; nf < 4; ++nf) {
      const u16* Vp = Vbase + (long)(nf * 16) * S_ + k0;
      vv[2 * nf] = *(const bf16x8*)(Vp);
      vv[2 * nf + 1] = *(const bf16x8*)(Vp + 32);
    }
    // ---- prefetch next K tile ----
    if (kt + 1 < end) {
      const int kn = (kt + 1) << 6;
#pragma unroll
      for (int nf = 0; nf < 4; ++nf) {
        const u16* Kp = Kbase + (long)(kn + nf * 16) * H_;
        kc[2 * nf] = *(const bf16x8*)(Kp);
        kc[2 * nf + 1] = *(const bf16x8*)(Kp + 32);
      }
    }

    if (kt == T - 1) {  // diagonal tile: causal mask
#pragma unroll
      for (int nf = 0; nf < 4; ++nf)
#pragma unroll
        for (int i = 0; i < 4; ++i) {
          const int k = k0 + nf * 16 + r;
          const int q = q0 + 4 * g + i;
          if (k > q) sf[nf][i] = -INFINITY;
        }
    }

    // ---- online softmax (rows in 16-lane groups) ----
    float fm[4];
#pragma unroll
    for (int i = 0; i < 4; ++i)
      fm[i] = fmaxf(fmaxf(sf[0][i], sf[1][i]), fmaxf(sf[2][i], sf[3][i]));
#pragma unroll
    for (int off = 8; off >= 1; off >>= 1)
#pragma unroll
      for (int i = 0; i < 4; ++i)
        fm[i] = fmaxf(fm[i], __shfl_xor(fm[i], off));

    float sc[4];
#pragma unroll
    for (int i = 0; i < 4; ++i) {
      const float mn = fmaxf(mrow[i], fm[i]);
      sc[i] = exp2f(mrow[i] - mn);
      mrow[i] = mn;
    }

    float ps[4] = {0.f, 0.f, 0.f, 0.f};
#pragma unroll
    for (int nf = 0; nf < 4; ++nf)
#pragma unroll
      for (int i = 0; i < 4; ++i) {
        const float p = exp2f(sf[nf][i] - mrow[i]);
        sf[nf][i] = p;
        ps[i] += p;
      }
#pragma unroll
    for (int off = 8; off >= 1; off >>= 1)
#pragma unroll
      for (int i = 0; i < 4; ++i)
        ps[i] += __shfl_xor(ps[i], off);

#pragma unroll
    for (int i = 0; i < 4; ++i) lrow[i] = lrow[i] * sc[i] + ps[i];
#pragma unroll
    for (int nf = 0; nf < 4; ++nf)
#pragma unroll
      for (int i = 0; i < 4; ++i) o[nf][i] *= sc[i];

    // ---- P -> LDS (bf16), re-fragment as PV A-operand ----
#pragma unroll
    for (int nf = 0; nf < 4; ++nf)
#pragma unroll
      for (int i = 0; i < 4; ++i)
        pw[(4 * g + i) * 72 + nf * 16 + r] = f2bf(sf[nf][i]);

    const bf16x8 pa0 = *(const bf16x8*)(pw + r * 72 + 8 * g);
    const bf16x8 pa1 = *(const bf16x8*)(pw + r * 72 + 32 + 8 * g);

    // ---- PV ----
#pragma unroll
    for (int nf = 0; nf < 4; ++nf) {
      o[nf] = __builtin_amdgcn_mfma_f32_16x16x32_bf16(pa0, vv[2 * nf], o[nf], 0, 0, 0);
      o[nf] = __builtin_amdgcn_mfma_f32_16x16x32_bf16(pa1, vv[2 * nf + 1], o[nf], 0, 0, 0);
    }
  }

  // ---- write partials to LDS ----
#pragma unroll
  for (int nf = 0; nf < 4; ++nf)
#pragma unroll
    for (int i = 0; i < 4; ++i)
      plo[w][4 * g + i][nf * 16 + r] = o[nf][i];
  if (r == 0) {
#pragma unroll
    for (int i = 0; i < 4; ++i) {
      pml[w][0][4 * g + i] = mrow[i];
      pml[w][1][4 * g + i] = lrow[i];
    }
  }
  __syncthreads();

  // ---- merge the two kv-halves; each wave writes 8 rows of one q-tile ----
  const int base = (w >> 1) << 1;
  const int hlf = w & 1;
  const int qq0 = ((base == 0) ? j : (127 - j)) << 4;
#pragma unroll
  for (int rr = 0; rr < 8; ++rr) {
    const int row = hlf * 8 + rr;
    const float mA = pml[base][0][row], mB = pml[base + 1][0][row];
    const float lA = pml[base][1][row], lB = pml[base + 1][1][row];
    const float M = fmaxf(mA, mB);
    const float ea = exp2f(mA - M), eb = exp2f(mB - M);
    const float inv = 1.f / (lA * ea + lB * eb);
    const float oo = plo[base][row][lane] * ea + plo[base + 1][row][lane] * eb;
    out[((long)(b * S_ + qq0 + row)) * H_ + lane] = oo * inv;
  }
}

extern "C" void kernel_launch(void* const* d_in, const int* in_sizes, int n_in,
                              void* d_out, int out_size, void* d_ws, size_t ws_size,
                              hipStream_t stream) {
  const float* x  = (const float*)d_in[0];
  const float* Wk = (const float*)d_in[1];
  const float* Wq = (const float*)d_in[2];
  const float* Wv = (const float*)d_in[3];
  float* out = (float*)d_out;

  u16* Qb = (u16*)d_ws;                                   // 2 MiB
  u16* Kb = Qb + (long)B_ * S_ * H_;                      // 2 MiB
  u16* Vt = Kb + (long)B_ * S_ * H_;                      // 2 MiB
  u16* Wt = Vt + (long)B_ * S_ * H_;                      // 384 KiB

  wprep_kernel<<<192, 256, 0, stream>>>(Wk, Wq, Wv, Wt);
  qkv_kernel<<<1024, 64, 0, stream>>>(x, Wt, Qb, Kb, Vt);
  attn3_kernel<<<B_ * 64, 256, 0, stream>>>(Qb, Kb, Vt, out);
}

// Round 4
// 100.525 us; speedup vs baseline: 4.0258x; 1.4618x over previous
//
#include <hip/hip_runtime.h>
#include <hip/hip_bf16.h>

#define B_ 8
#define S_ 2048
#define D_ 1024
#define H_ 64

typedef __attribute__((ext_vector_type(8))) short bf16x8;
typedef __attribute__((ext_vector_type(4))) float f32x4;
typedef __attribute__((ext_vector_type(4))) unsigned short u16x4;
typedef unsigned short u16;

// fold 1/sqrt(64) and log2(e) into Q so softmax can use exp2
#define QSCALE 0.18033688011112042f

static __device__ __forceinline__ u16 f2bf(float f) {
  union { float f; unsigned u; } v; v.f = f;
  unsigned r = v.u + 0x7FFFu + ((v.u >> 16) & 1u);
  return (u16)(r >> 16);
}

// Build Wt [192][1024] bf16: rows 0..63 = Wq cols, 64..127 = Wk, 128..191 = Wv.
__global__ __launch_bounds__(256) void wprep_kernel(const float* __restrict__ Wk,
                                                    const float* __restrict__ Wq,
                                                    const float* __restrict__ Wv,
                                                    u16* __restrict__ Wt) {
  const int c = blockIdx.x;  // 0..191
  const float* W = (c < 64) ? Wq : ((c < 128) ? Wk : Wv);
  const int cc = c & 63;
  for (int d = threadIdx.x; d < D_; d += blockDim.x)
    Wt[c * D_ + d] = f2bf(W[d * H_ + cc]);
}

// QKV projection with 4-way K-split.
// Block = 256 threads = 4 waves, all computing the SAME 16 rows x 192 cols;
// wave w handles K range [w*256, (w+1)*256). LDS tree-reduce, wave 0 writes.
// Grid = 1024 blocks -> 4096 waves = 4/SIMD.
__global__ __launch_bounds__(256) void qkv_kernel(const float* __restrict__ x,
                                                  const u16* __restrict__ Wt,
                                                  u16* __restrict__ Qb,
                                                  u16* __restrict__ Kb,
                                                  u16* __restrict__ Vt) {
  __shared__ float red[2][64][49];  // ~25 KB, stride 49 -> conflict-free

  const long row0 = (long)blockIdx.x * 16;
  const int w = threadIdx.x >> 6;
  const int lane = threadIdx.x & 63;
  const int r = lane & 15;
  const int g = lane >> 4;

  f32x4 acc[12];
#pragma unroll
  for (int nf = 0; nf < 12; ++nf) acc[nf] = (f32x4){0.f, 0.f, 0.f, 0.f};

  const float* xp = x + (row0 + r) * (long)D_ + w * 256 + 8 * g;
  const u16* wp = Wt + (long)r * D_ + w * 256 + 8 * g;

#pragma unroll 2
  for (int k0 = 0; k0 < 256; k0 += 32) {
    float4 lo = *(const float4*)(xp);
    float4 hi = *(const float4*)(xp + 4);
    bf16x8 a;
    a[0] = (short)f2bf(lo.x); a[1] = (short)f2bf(lo.y);
    a[2] = (short)f2bf(lo.z); a[3] = (short)f2bf(lo.w);
    a[4] = (short)f2bf(hi.x); a[5] = (short)f2bf(hi.y);
    a[6] = (short)f2bf(hi.z); a[7] = (short)f2bf(hi.w);
#pragma unroll
    for (int nf = 0; nf < 12; ++nf) {
      const bf16x8 b = *(const bf16x8*)(wp + (long)nf * 16 * D_);
      acc[nf] = __builtin_amdgcn_mfma_f32_16x16x32_bf16(a, b, acc[nf], 0, 0, 0);
    }
    xp += 32; wp += 32;
  }

  // ---- cross-wave reduce: {1,3} -> LDS; {0,2} add; 2 -> LDS; 0 adds ----
  if (w == 1 || w == 3) {
    float* dst = &red[w >> 1][lane][0];
#pragma unroll
    for (int nf = 0; nf < 12; ++nf)
#pragma unroll
      for (int i = 0; i < 4; ++i) dst[nf * 4 + i] = acc[nf][i];
  }
  __syncthreads();
  if (w == 0 || w == 2) {
    const float* src = &red[w >> 1][lane][0];
#pragma unroll
    for (int nf = 0; nf < 12; ++nf)
#pragma unroll
      for (int i = 0; i < 4; ++i) acc[nf][i] += src[nf * 4 + i];
  }
  __syncthreads();
  if (w == 2) {
    float* dst = &red[0][lane][0];
#pragma unroll
    for (int nf = 0; nf < 12; ++nf)
#pragma unroll
      for (int i = 0; i < 4; ++i) dst[nf * 4 + i] = acc[nf][i];
  }
  __syncthreads();
  if (w != 0) return;

  const float* src = &red[0][lane][0];
#pragma unroll
  for (int nf = 0; nf < 12; ++nf)
#pragma unroll
    for (int i = 0; i < 4; ++i) acc[nf][i] += src[nf * 4 + i];

  // ---- epilogue (wave 0 only) ----
  const int bb = (int)(row0 >> 11);
  const int srow = (int)(row0 & 2047);

#pragma unroll
  for (int nf = 0; nf < 4; ++nf) {   // Q: cols 0..63, pre-scaled
    const int col = nf * 16 + r;
#pragma unroll
    for (int i = 0; i < 4; ++i)
      Qb[(row0 + 4 * g + i) * H_ + col] = f2bf(acc[nf][i] * QSCALE);
  }
#pragma unroll
  for (int nf = 4; nf < 8; ++nf) {   // K: cols 64..127
    const int col = (nf - 4) * 16 + r;
#pragma unroll
    for (int i = 0; i < 4; ++i)
      Kb[(row0 + 4 * g + i) * H_ + col] = f2bf(acc[nf][i]);
  }
#pragma unroll
  for (int nf = 8; nf < 12; ++nf) {  // V^T: [b][h][s], 4 consecutive s -> 8B store
    const int col = (nf - 8) * 16 + r;
    u16x4 vp;
#pragma unroll
    for (int i = 0; i < 4; ++i) vp[i] = f2bf(acc[nf][i]);
    *(u16x4*)(Vt + ((long)(bb * H_ + col)) * S_ + srow + 4 * g) = vp;
  }
}

// MFMA causal flash attention with 2-way KV split.
// Block = 4 waves: waves {0,1} = q-tile j (kv halves 0,1), waves {2,3} = q-tile 127-j.
// Grid = 8 batches x 64 pairs = 512 blocks -> 2 blocks/CU.
__global__ __launch_bounds__(256) void attn3_kernel(const u16* __restrict__ Qb,
                                                    const u16* __restrict__ Kb,
                                                    const u16* __restrict__ Vt,
                                                    float* __restrict__ out) {
  __shared__ u16 plds[4][16 * 72];
  __shared__ float plo[4][16][68];
  __shared__ float pml[4][2][16];

  const int b = blockIdx.x >> 6;
  const int j = blockIdx.x & 63;
  const int w = threadIdx.x >> 6;
  const int lane = threadIdx.x & 63;
  const int r = lane & 15;
  const int g = lane >> 4;

  const int qt = (w < 2) ? j : (127 - j);
  const int s = w & 1;
  const int q0 = qt << 4;
  const int T = (qt >> 2) + 1;          // # of 64-wide kv tiles
  const int half = (T + 1) >> 1;
  const int start = s ? half : 0;
  const int end = s ? T : half;

  // Q A-fragments (hoisted)
  const u16* Qp = Qb + ((long)(b * S_ + q0 + r)) * H_ + 8 * g;
  const bf16x8 aq0 = *(const bf16x8*)Qp;
  const bf16x8 aq1 = *(const bf16x8*)(Qp + 32);

  const u16* Kbase = Kb + (long)b * S_ * H_ + (long)r * H_ + 8 * g;
  const u16* Vbase = Vt + (long)b * H_ * S_ + (long)r * S_ + 8 * g;

  f32x4 o[4];
#pragma unroll
  for (int nf = 0; nf < 4; ++nf) o[nf] = (f32x4){0.f, 0.f, 0.f, 0.f};
  float mrow[4] = {-INFINITY, -INFINITY, -INFINITY, -INFINITY};
  float lrow[4] = {0.f, 0.f, 0.f, 0.f};

  u16* pw = plds[w];

  bf16x8 kc[8];
  if (start < end) {
    const int k0 = start << 6;
#pragma unroll
    for (int nf = 0; nf < 4; ++nf) {
      const u16* Kp = Kbase + (long)(k0 + nf * 16) * H_;
      kc[2 * nf] = *(const bf16x8*)(Kp);
      kc[2 * nf + 1] = *(const bf16x8*)(Kp + 32);
    }
  }

  for (int kt = start; kt < end; ++kt) {
    const int k0 = kt << 6;

    // ---- QK^T ----
    f32x4 sf[4];
#pragma unroll
    for (int nf = 0; nf < 4; ++nf) {
      f32x4 t = (f32x4){0.f, 0.f, 0.f, 0.f};
      t = __builtin_amdgcn_mfma_f32_16x16x32_bf16(aq0, kc[2 * nf], t, 0, 0, 0);
      t = __builtin_amdgcn_mfma_f32_16x16x32_bf16(aq1, kc[2 * nf + 1], t, 0, 0, 0);
      sf[nf] = t;
    }

    // ---- early V loads (fly under softmax) ----
    bf16x8 vv[8];
#pragma unroll
    for (int nf = 0; nf < 4; ++nf) {
      const u16* Vp = Vbase + (long)(nf * 16) * S_ + k0;
      vv[2 * nf] = *(const bf16x8*)(Vp);
      vv[2 * nf + 1] = *(const bf16x8*)(Vp + 32);
    }
    // ---- prefetch next K tile ----
    if (kt + 1 < end) {
      const int kn = (kt + 1) << 6;
#pragma unroll
      for (int nf = 0; nf < 4; ++nf) {
        const u16* Kp = Kbase + (long)(kn + nf * 16) * H_;
        kc[2 * nf] = *(const bf16x8*)(Kp);
        kc[2 * nf + 1] = *(const bf16x8*)(Kp + 32);
      }
    }

    if (kt == T - 1) {  // diagonal tile: causal mask
#pragma unroll
      for (int nf = 0; nf < 4; ++nf)
#pragma unroll
        for (int i = 0; i < 4; ++i) {
          const int k = k0 + nf * 16 + r;
          const int q = q0 + 4 * g + i;
          if (k > q) sf[nf][i] = -INFINITY;
        }
    }

    // ---- online softmax (rows in 16-lane groups) ----
    float fm[4];
#pragma unroll
    for (int i = 0; i < 4; ++i)
      fm[i] = fmaxf(fmaxf(sf[0][i], sf[1][i]), fmaxf(sf[2][i], sf[3][i]));
#pragma unroll
    for (int off = 8; off >= 1; off >>= 1)
#pragma unroll
      for (int i = 0; i < 4; ++i)
        fm[i] = fmaxf(fm[i], __shfl_xor(fm[i], off));

    float sc[4];
#pragma unroll
    for (int i = 0; i < 4; ++i) {
      const float mn = fmaxf(mrow[i], fm[i]);
      sc[i] = exp2f(mrow[i] - mn);
      mrow[i] = mn;
    }

    float ps[4] = {0.f, 0.f, 0.f, 0.f};
#pragma unroll
    for (int nf = 0; nf < 4; ++nf)
#pragma unroll
      for (int i = 0; i < 4; ++i) {
        const float p = exp2f(sf[nf][i] - mrow[i]);
        sf[nf][i] = p;
        ps[i] += p;
      }
#pragma unroll
    for (int off = 8; off >= 1; off >>= 1)
#pragma unroll
      for (int i = 0; i < 4; ++i)
        ps[i] += __shfl_xor(ps[i], off);

#pragma unroll
    for (int i = 0; i < 4; ++i) lrow[i] = lrow[i] * sc[i] + ps[i];
#pragma unroll
    for (int nf = 0; nf < 4; ++nf)
#pragma unroll
      for (int i = 0; i < 4; ++i) o[nf][i] *= sc[i];

    // ---- P -> LDS (bf16), re-fragment as PV A-operand ----
#pragma unroll
    for (int nf = 0; nf < 4; ++nf)
#pragma unroll
      for (int i = 0; i < 4; ++i)
        pw[(4 * g + i) * 72 + nf * 16 + r] = f2bf(sf[nf][i]);

    const bf16x8 pa0 = *(const bf16x8*)(pw + r * 72 + 8 * g);
    const bf16x8 pa1 = *(const bf16x8*)(pw + r * 72 + 32 + 8 * g);

    // ---- PV ----
#pragma unroll
    for (int nf = 0; nf < 4; ++nf) {
      o[nf] = __builtin_amdgcn_mfma_f32_16x16x32_bf16(pa0, vv[2 * nf], o[nf], 0, 0, 0);
      o[nf] = __builtin_amdgcn_mfma_f32_16x16x32_bf16(pa1, vv[2 * nf + 1], o[nf], 0, 0, 0);
    }
  }

  // ---- write partials to LDS ----
#pragma unroll
  for (int nf = 0; nf < 4; ++nf)
#pragma unroll
    for (int i = 0; i < 4; ++i)
      plo[w][4 * g + i][nf * 16 + r] = o[nf][i];
  if (r == 0) {
#pragma unroll
    for (int i = 0; i < 4; ++i) {
      pml[w][0][4 * g + i] = mrow[i];
      pml[w][1][4 * g + i] = lrow[i];
    }
  }
  __syncthreads();

  // ---- merge the two kv-halves; each wave writes 8 rows of one q-tile ----
  const int base = (w >> 1) << 1;
  const int hlf = w & 1;
  const int qq0 = ((base == 0) ? j : (127 - j)) << 4;
#pragma unroll
  for (int rr = 0; rr < 8; ++rr) {
    const int row = hlf * 8 + rr;
    const float mA = pml[base][0][row], mB = pml[base + 1][0][row];
    const float lA = pml[base][1][row], lB = pml[base + 1][1][row];
    const float M = fmaxf(mA, mB);
    const float ea = exp2f(mA - M), eb = exp2f(mB - M);
    const float inv = 1.f / (lA * ea + lB * eb);
    const float oo = plo[base][row][lane] * ea + plo[base + 1][row][lane] * eb;
    out[((long)(b * S_ + qq0 + row)) * H_ + lane] = oo * inv;
  }
}

extern "C" void kernel_launch(void* const* d_in, const int* in_sizes, int n_in,
                              void* d_out, int out_size, void* d_ws, size_t ws_size,
                              hipStream_t stream) {
  const float* x  = (const float*)d_in[0];
  const float* Wk = (const float*)d_in[1];
  const float* Wq = (const float*)d_in[2];
  const float* Wv = (const float*)d_in[3];
  float* out = (float*)d_out;

  u16* Qb = (u16*)d_ws;                                   // 2 MiB
  u16* Kb = Qb + (long)B_ * S_ * H_;                      // 2 MiB
  u16* Vt = Kb + (long)B_ * S_ * H_;                      // 2 MiB
  u16* Wt = Vt + (long)B_ * S_ * H_;                      // 384 KiB

  wprep_kernel<<<192, 256, 0, stream>>>(Wk, Wq, Wv, Wt);
  qkv_kernel<<<1024, 256, 0, stream>>>(x, Wt, Qb, Kb, Vt);
  attn3_kernel<<<B_ * 64, 256, 0, stream>>>(Qb, Kb, Vt, out);
}

// Round 5
// 79.906 us; speedup vs baseline: 5.0646x; 1.2580x over previous
//
#include <hip/hip_runtime.h>
#include <hip/hip_bf16.h>

#define B_ 8
#define S_ 2048
#define D_ 1024
#define H_ 64

typedef __attribute__((ext_vector_type(8))) short bf16x8;
typedef __attribute__((ext_vector_type(4))) float f32x4;
typedef __attribute__((ext_vector_type(4))) unsigned short u16x4;
typedef unsigned short u16;

// fold 1/sqrt(64) and log2(e) into Q so softmax can use exp2
#define QSCALE 0.18033688011112042f

static __device__ __forceinline__ u16 f2bf(float f) {
  union { float f; unsigned u; } v; v.f = f;
  unsigned r = v.u + 0x7FFFu + ((v.u >> 16) & 1u);
  return (u16)(r >> 16);
}

// Build Wt [192][1024] bf16: rows 0..63 = Wq cols, 64..127 = Wk, 128..191 = Wv.
__global__ __launch_bounds__(256) void wprep_kernel(const float* __restrict__ Wk,
                                                    const float* __restrict__ Wq,
                                                    const float* __restrict__ Wv,
                                                    u16* __restrict__ Wt) {
  const int c = blockIdx.x;  // 0..191
  const float* W = (c < 64) ? Wq : ((c < 128) ? Wk : Wv);
  const int cc = c & 63;
  for (int d = threadIdx.x; d < D_; d += blockDim.x)
    Wt[c * D_ + d] = f2bf(W[d * H_ + cc]);
}

// QKV projection, 32 rows/block, 4-way K-split, explicit reg double-buffering.
// Block = 4 waves; wave w covers K range [w*256,(w+1)*256) of the SAME
// 32 rows x 192 cols. acc[2][12]. LDS tree-reduce, wave 0 writes epilogue.
// Grid = 512 blocks = 2/CU; 2048 waves = 2/SIMD (VGPR-matched).
__global__ __launch_bounds__(256, 2) void qkv_kernel(const float* __restrict__ x,
                                                     const u16* __restrict__ Wt,
                                                     u16* __restrict__ Qb,
                                                     u16* __restrict__ Kb,
                                                     u16* __restrict__ Vt) {
  __shared__ float red[2][64][108];  // stride 27 words (odd) -> conflict-free b128

  const long row0 = (long)blockIdx.x * 32;
  const int w = threadIdx.x >> 6;
  const int lane = threadIdx.x & 63;
  const int r = lane & 15;
  const int g = lane >> 4;

  f32x4 acc[2][12];
#pragma unroll
  for (int mi = 0; mi < 2; ++mi)
#pragma unroll
    for (int nf = 0; nf < 12; ++nf) acc[mi][nf] = (f32x4){0.f, 0.f, 0.f, 0.f};

  const float* xp0 = x + (row0 + r) * (long)D_ + w * 256 + 8 * g;
  const u16* wp0 = Wt + (long)r * D_ + w * 256 + 8 * g;

  float4 X0[2][4], X1[2][4];   // [mi][q]: q = {+0,+4,+32,+36} within a 64-k chunk
  bf16x8 W0[12], W1[12];

#define ISSUE_X(XB, kk)                                                    \
  {                                                                        \
    _Pragma("unroll") for (int mi = 0; mi < 2; ++mi) {                     \
      const float* p = xp0 + (long)mi * 16 * D_ + (kk);                    \
      XB[mi][0] = *(const float4*)(p);                                     \
      XB[mi][1] = *(const float4*)(p + 4);                                 \
      XB[mi][2] = *(const float4*)(p + 32);                                \
      XB[mi][3] = *(const float4*)(p + 36);                                \
    }                                                                      \
  }

#define ISSUE_W(WB, kofs)                                                  \
  {                                                                        \
    _Pragma("unroll") for (int nf = 0; nf < 12; ++nf)                      \
      WB[nf] = *(const bf16x8*)(wp0 + (long)nf * 16 * D_ + (kofs));        \
  }

#define COMPUTE(XB, half, WB)                                              \
  {                                                                        \
    bf16x8 a0, a1;                                                         \
    _Pragma("unroll") for (int mi = 0; mi < 2; ++mi) {                     \
      const float4 lo = XB[mi][2 * (half)];                                \
      const float4 hi = XB[mi][2 * (half) + 1];                            \
      bf16x8 t;                                                            \
      t[0] = (short)f2bf(lo.x); t[1] = (short)f2bf(lo.y);                  \
      t[2] = (short)f2bf(lo.z); t[3] = (short)f2bf(lo.w);                  \
      t[4] = (short)f2bf(hi.x); t[5] = (short)f2bf(hi.y);                  \
      t[6] = (short)f2bf(hi.z); t[7] = (short)f2bf(hi.w);                  \
      if (mi == 0) a0 = t; else a1 = t;                                    \
    }                                                                      \
    _Pragma("unroll") for (int nf = 0; nf < 12; ++nf) {                    \
      acc[0][nf] = __builtin_amdgcn_mfma_f32_16x16x32_bf16(a0, WB[nf], acc[0][nf], 0, 0, 0); \
      acc[1][nf] = __builtin_amdgcn_mfma_f32_16x16x32_bf16(a1, WB[nf], acc[1][nf], 0, 0, 0); \
    }                                                                      \
  }

#define CHUNK(XC, XN, kk)                                                  \
  {                                                                        \
    if ((kk) + 64 < 256) ISSUE_X(XN, (kk) + 64);                           \
    ISSUE_W(W1, (kk) + 32);                                                \
    COMPUTE(XC, 0, W0);                                                    \
    if ((kk) + 64 < 256) ISSUE_W(W0, (kk) + 64);                           \
    COMPUTE(XC, 1, W1);                                                    \
  }

  ISSUE_X(X0, 0);
  ISSUE_W(W0, 0);
  CHUNK(X0, X1, 0);
  CHUNK(X1, X0, 64);
  CHUNK(X0, X1, 128);
  CHUNK(X1, X0, 192);

#undef CHUNK
#undef COMPUTE
#undef ISSUE_W
#undef ISSUE_X

  // ---- cross-wave reduce: {1,3} -> LDS; {0,2} add; 2 -> LDS; 0 adds ----
  if (w == 1 || w == 3) {
    float* dst = &red[w >> 1][lane][0];
#pragma unroll
    for (int mi = 0; mi < 2; ++mi)
#pragma unroll
      for (int nf = 0; nf < 12; ++nf)
        *(f32x4*)&dst[(mi * 12 + nf) * 4] = acc[mi][nf];
  }
  __syncthreads();
  if (w == 0 || w == 2) {
    const float* src = &red[w >> 1][lane][0];
#pragma unroll
    for (int mi = 0; mi < 2; ++mi)
#pragma unroll
      for (int nf = 0; nf < 12; ++nf)
        acc[mi][nf] += *(const f32x4*)&src[(mi * 12 + nf) * 4];
  }
  __syncthreads();
  if (w == 2) {
    float* dst = &red[0][lane][0];
#pragma unroll
    for (int mi = 0; mi < 2; ++mi)
#pragma unroll
      for (int nf = 0; nf < 12; ++nf)
        *(f32x4*)&dst[(mi * 12 + nf) * 4] = acc[mi][nf];
  }
  __syncthreads();
  if (w != 0) return;

  {
    const float* src = &red[0][lane][0];
#pragma unroll
    for (int mi = 0; mi < 2; ++mi)
#pragma unroll
      for (int nf = 0; nf < 12; ++nf)
        acc[mi][nf] += *(const f32x4*)&src[(mi * 12 + nf) * 4];
  }

  // ---- epilogue (wave 0 only) ----
  const int bb = (int)(row0 >> 11);
  const int srow = (int)(row0 & 2047);

#pragma unroll
  for (int mi = 0; mi < 2; ++mi) {
#pragma unroll
    for (int nf = 0; nf < 4; ++nf) {   // Q: cols 0..63, pre-scaled
      const int col = nf * 16 + r;
#pragma unroll
      for (int i = 0; i < 4; ++i)
        Qb[(row0 + mi * 16 + 4 * g + i) * H_ + col] = f2bf(acc[mi][nf][i] * QSCALE);
    }
#pragma unroll
    for (int nf = 4; nf < 8; ++nf) {   // K: cols 64..127
      const int col = (nf - 4) * 16 + r;
#pragma unroll
      for (int i = 0; i < 4; ++i)
        Kb[(row0 + mi * 16 + 4 * g + i) * H_ + col] = f2bf(acc[mi][nf][i]);
    }
#pragma unroll
    for (int nf = 8; nf < 12; ++nf) {  // V^T: [b][h][s], 4 consecutive s -> 8B store
      const int col = (nf - 8) * 16 + r;
      u16x4 vp;
#pragma unroll
      for (int i = 0; i < 4; ++i) vp[i] = f2bf(acc[mi][nf][i]);
      *(u16x4*)(Vt + ((long)(bb * H_ + col)) * S_ + srow + mi * 16 + 4 * g) = vp;
    }
  }
}

// MFMA causal flash attention with 2-way KV split.
// Block = 4 waves: waves {0,1} = q-tile j (kv halves 0,1), waves {2,3} = q-tile 127-j.
// Grid = 8 batches x 64 pairs = 512 blocks -> 2 blocks/CU.
__global__ __launch_bounds__(256) void attn3_kernel(const u16* __restrict__ Qb,
                                                    const u16* __restrict__ Kb,
                                                    const u16* __restrict__ Vt,
                                                    float* __restrict__ out) {
  __shared__ u16 plds[4][16 * 72];
  __shared__ float plo[4][16][68];
  __shared__ float pml[4][2][16];

  const int b = blockIdx.x >> 6;
  const int j = blockIdx.x & 63;
  const int w = threadIdx.x >> 6;
  const int lane = threadIdx.x & 63;
  const int r = lane & 15;
  const int g = lane >> 4;

  const int qt = (w < 2) ? j : (127 - j);
  const int s = w & 1;
  const int q0 = qt << 4;
  const int T = (qt >> 2) + 1;          // # of 64-wide kv tiles
  const int half = (T + 1) >> 1;
  const int start = s ? half : 0;
  const int end = s ? T : half;

  // Q A-fragments (hoisted)
  const u16* Qp = Qb + ((long)(b * S_ + q0 + r)) * H_ + 8 * g;
  const bf16x8 aq0 = *(const bf16x8*)Qp;
  const bf16x8 aq1 = *(const bf16x8*)(Qp + 32);

  const u16* Kbase = Kb + (long)b * S_ * H_ + (long)r * H_ + 8 * g;
  const u16* Vbase = Vt + (long)b * H_ * S_ + (long)r * S_ + 8 * g;

  f32x4 o[4];
#pragma unroll
  for (int nf = 0; nf < 4; ++nf) o[nf] = (f32x4){0.f, 0.f, 0.f, 0.f};
  float mrow[4] = {-INFINITY, -INFINITY, -INFINITY, -INFINITY};
  float lrow[4] = {0.f, 0.f, 0.f, 0.f};

  u16* pw = plds[w];

  bf16x8 kc[8];
  if (start < end) {
    const int k0 = start << 6;
#pragma unroll
    for (int nf = 0; nf < 4; ++nf) {
      const u16* Kp = Kbase + (long)(k0 + nf * 16) * H_;
      kc[2 * nf] = *(const bf16x8*)(Kp);
      kc[2 * nf + 1] = *(const bf16x8*)(Kp + 32);
    }
  }

  for (int kt = start; kt < end; ++kt) {
    const int k0 = kt << 6;

    // ---- QK^T ----
    f32x4 sf[4];
#pragma unroll
    for (int nf = 0; nf < 4; ++nf) {
      f32x4 t = (f32x4){0.f, 0.f, 0.f, 0.f};
      t = __builtin_amdgcn_mfma_f32_16x16x32_bf16(aq0, kc[2 * nf], t, 0, 0, 0);
      t = __builtin_amdgcn_mfma_f32_16x16x32_bf16(aq1, kc[2 * nf + 1], t, 0, 0, 0);
      sf[nf] = t;
    }

    // ---- early V loads (fly under softmax) ----
    bf16x8 vv[8];
#pragma unroll
    for (int nf = 0; nf < 4; ++nf) {
      const u16* Vp = Vbase + (long)(nf * 16) * S_ + k0;
      vv[2 * nf] = *(const bf16x8*)(Vp);
      vv[2 * nf + 1] = *(const bf16x8*)(Vp + 32);
    }
    // ---- prefetch next K tile ----
    if (kt + 1 < end) {
      const int kn = (kt + 1) << 6;
#pragma unroll
      for (int nf = 0; nf < 4; ++nf) {
        const u16* Kp = Kbase + (long)(kn + nf * 16) * H_;
        kc[2 * nf] = *(const bf16x8*)(Kp);
        kc[2 * nf + 1] = *(const bf16x8*)(Kp + 32);
      }
    }

    if (kt == T - 1) {  // diagonal tile: causal mask
#pragma unroll
      for (int nf = 0; nf < 4; ++nf)
#pragma unroll
        for (int i = 0; i < 4; ++i) {
          const int k = k0 + nf * 16 + r;
          const int q = q0 + 4 * g + i;
          if (k > q) sf[nf][i] = -INFINITY;
        }
    }

    // ---- online softmax (rows in 16-lane groups) ----
    float fm[4];
#pragma unroll
    for (int i = 0; i < 4; ++i)
      fm[i] = fmaxf(fmaxf(sf[0][i], sf[1][i]), fmaxf(sf[2][i], sf[3][i]));
#pragma unroll
    for (int off = 8; off >= 1; off >>= 1)
#pragma unroll
      for (int i = 0; i < 4; ++i)
        fm[i] = fmaxf(fm[i], __shfl_xor(fm[i], off));

    float sc[4];
#pragma unroll
    for (int i = 0; i < 4; ++i) {
      const float mn = fmaxf(mrow[i], fm[i]);
      sc[i] = exp2f(mrow[i] - mn);
      mrow[i] = mn;
    }

    float ps[4] = {0.f, 0.f, 0.f, 0.f};
#pragma unroll
    for (int nf = 0; nf < 4; ++nf)
#pragma unroll
      for (int i = 0; i < 4; ++i) {
        const float p = exp2f(sf[nf][i] - mrow[i]);
        sf[nf][i] = p;
        ps[i] += p;
      }
#pragma unroll
    for (int off = 8; off >= 1; off >>= 1)
#pragma unroll
      for (int i = 0; i < 4; ++i)
        ps[i] += __shfl_xor(ps[i], off);

#pragma unroll
    for (int i = 0; i < 4; ++i) lrow[i] = lrow[i] * sc[i] + ps[i];
#pragma unroll
    for (int nf = 0; nf < 4; ++nf)
#pragma unroll
      for (int i = 0; i < 4; ++i) o[nf][i] *= sc[i];

    // ---- P -> LDS (bf16), re-fragment as PV A-operand ----
#pragma unroll
    for (int nf = 0; nf < 4; ++nf)
#pragma unroll
      for (int i = 0; i < 4; ++i)
        pw[(4 * g + i) * 72 + nf * 16 + r] = f2bf(sf[nf][i]);

    const bf16x8 pa0 = *(const bf16x8*)(pw + r * 72 + 8 * g);
    const bf16x8 pa1 = *(const bf16x8*)(pw + r * 72 + 32 + 8 * g);

    // ---- PV ----
#pragma unroll
    for (int nf = 0; nf < 4; ++nf) {
      o[nf] = __builtin_amdgcn_mfma_f32_16x16x32_bf16(pa0, vv[2 * nf], o[nf], 0, 0, 0);
      o[nf] = __builtin_amdgcn_mfma_f32_16x16x32_bf16(pa1, vv[2 * nf + 1], o[nf], 0, 0, 0);
    }
  }

  // ---- write partials to LDS ----
#pragma unroll
  for (int nf = 0; nf < 4; ++nf)
#pragma unroll
    for (int i = 0; i < 4; ++i)
      plo[w][4 * g + i][nf * 16 + r] = o[nf][i];
  if (r == 0) {
#pragma unroll
    for (int i = 0; i < 4; ++i) {
      pml[w][0][4 * g + i] = mrow[i];
      pml[w][1][4 * g + i] = lrow[i];
    }
  }
  __syncthreads();

  // ---- merge the two kv-halves; each wave writes 8 rows of one q-tile ----
  const int base = (w >> 1) << 1;
  const int hlf = w & 1;
  const int qq0 = ((base == 0) ? j : (127 - j)) << 4;
#pragma unroll
  for (int rr = 0; rr < 8; ++rr) {
    const int row = hlf * 8 + rr;
    const float mA = pml[base][0][row], mB = pml[base + 1][0][row];
    const float lA = pml[base][1][row], lB = pml[base + 1][1][row];
    const float M = fmaxf(mA, mB);
    const float ea = exp2f(mA - M), eb = exp2f(mB - M);
    const float inv = 1.f / (lA * ea + lB * eb);
    const float oo = plo[base][row][lane] * ea + plo[base + 1][row][lane] * eb;
    out[((long)(b * S_ + qq0 + row)) * H_ + lane] = oo * inv;
  }
}

extern "C" void kernel_launch(void* const* d_in, const int* in_sizes, int n_in,
                              void* d_out, int out_size, void* d_ws, size_t ws_size,
                              hipStream_t stream) {
  const float* x  = (const float*)d_in[0];
  const float* Wk = (const float*)d_in[1];
  const float* Wq = (const float*)d_in[2];
  const float* Wv = (const float*)d_in[3];
  float* out = (float*)d_out;

  u16* Qb = (u16*)d_ws;                                   // 2 MiB
  u16* Kb = Qb + (long)B_ * S_ * H_;                      // 2 MiB
  u16* Vt = Kb + (long)B_ * S_ * H_;                      // 2 MiB
  u16* Wt = Vt + (long)B_ * S_ * H_;                      // 384 KiB

  wprep_kernel<<<192, 256, 0, stream>>>(Wk, Wq, Wv, Wt);
  qkv_kernel<<<512, 256, 0, stream>>>(x, Wt, Qb, Kb, Vt);
  attn3_kernel<<<B_ * 64, 256, 0, stream>>>(Qb, Kb, Vt, out);
}